// Round 9
// baseline (178.092 us; speedup 1.0000x reference)
//
#include <hip/hip_runtime.h>
#include <hip/hip_bf16.h>
#include <stdint.h>
#include <stddef.h>

#define SEQ   2048
#define NBATCH 4
#define NHEAD  8
#define DMODEL 512

typedef __attribute__((ext_vector_type(8))) short bf16x8;
typedef __attribute__((ext_vector_type(4))) float f32x4;
typedef __attribute__((ext_vector_type(16))) float f32x16;

#define MFMA16(a, b, c) __builtin_amdgcn_mfma_f32_16x16x32_bf16(a, b, c, 0, 0, 0)
#define MFMA32(a, b, c) __builtin_amdgcn_mfma_f32_32x32x16_bf16(a, b, c, 0, 0, 0)

// 0.125 (softmax scale) * log2(e): QK^T lands in log2 domain -> P = exp2(s)
#define QSCALE 0.18033688011112042f

__device__ __forceinline__ float bf2f(ushort u) {
  union { uint32_t i; float f; } v; v.i = ((uint32_t)u) << 16; return v.f;
}
__device__ __forceinline__ ushort f2bf(float f) {
  union { float f; uint32_t i; } v; v.f = f;
  uint32_t u = v.i;
  return (ushort)((u + 0x7fffu + ((u >> 16) & 1u)) >> 16);
}
__device__ __forceinline__ uint32_t cvtpk(float lo, float hi) {
  uint32_t d;
  asm("v_cvt_pk_bf16_f32 %0, %1, %2" : "=v"(d) : "v"(lo), "v"(hi));
  return d;
}

#if __has_builtin(__builtin_amdgcn_global_load_lds)
__device__ __forceinline__ void gload16(const void* g, void* l) {
  __builtin_amdgcn_global_load_lds(
      (const __attribute__((address_space(1))) void*)g,
      (__attribute__((address_space(3))) void*)l, 16, 0, 0);
}
#define GLOAD_DIRECT 1
#else
#define GLOAD_DIRECT 0
#endif

// ---------------------------------------------------------------------------
// f32 -> bf16 elementwise convert. n8 = elements/8.
// ---------------------------------------------------------------------------
__global__ __launch_bounds__(256) void cvt_k(const float* __restrict__ in,
                                             ushort* __restrict__ out, int n8) {
  int i = blockIdx.x * 256 + threadIdx.x;
  if (i >= n8) return;
  const float4* p = (const float4*)(in + (size_t)i * 8);
  float4 a = p[0], b = p[1];
  union { int4 v; ushort u[8]; } o;
  o.u[0] = f2bf(a.x); o.u[1] = f2bf(a.y); o.u[2] = f2bf(a.z); o.u[3] = f2bf(a.w);
  o.u[4] = f2bf(b.x); o.u[5] = f2bf(b.y); o.u[6] = f2bf(b.z); o.u[7] = f2bf(b.w);
  *(int4*)(out + (size_t)i * 8) = o.v;
}

// ---------------------------------------------------------------------------
// All four weight transposes in one launch. W f32 [512,N] -> Wt bf16 [N,512].
// ---------------------------------------------------------------------------
__global__ __launch_bounds__(256) void wtrans_k(const float* __restrict__ Wq,
                                                const float* __restrict__ Wkv,
                                                const float* __restrict__ Wg,
                                                const float* __restrict__ Wo,
                                                ushort* __restrict__ WT,
                                                ushort* __restrict__ WoT) {
  __shared__ ushort tile[32][33];
  int bx = blockIdx.x;
  const float* W;
  ushort* dst;
  int N, nt;
  if (bx < 16)       { W = Wq;  dst = WT;              N = 512;  nt = bx; }
  else if (bx < 48)  { W = Wkv; dst = WT + 512 * 512;  N = 1024; nt = bx - 16; }
  else if (bx < 64)  { W = Wg;  dst = WT + 1536 * 512; N = 512;  nt = bx - 48; }
  else               { W = Wo;  dst = WoT;             N = 512;  nt = bx - 64; }
  int t = threadIdx.x;
  int n0 = nt * 32, k0 = blockIdx.y * 32;
  int r = t >> 3, c = (t & 7) * 4;
#pragma unroll
  for (int j = 0; j < 4; j++)
    tile[r][c + j] = f2bf(W[(size_t)(k0 + r) * N + n0 + c + j]);
  __syncthreads();
#pragma unroll
  for (int j = 0; j < 4; j++)
    dst[(size_t)(n0 + r) * 512 + k0 + c + j] = tile[c + j][r];
}

// ---------------------------------------------------------------------------
// bf16 transpose for V: vbuf [B*SEQ][512] head cols -> vT [bh][64][2048].
// 8B vectorized load/store (G13).
// ---------------------------------------------------------------------------
__global__ __launch_bounds__(256) void vtrans_k(const ushort* __restrict__ vbuf,
                                                ushort* __restrict__ vT) {
  __shared__ ushort tile[32][33];
  int t = threadIdx.x;
  int n0 = blockIdx.x * 32;
  int d0 = blockIdx.y * 32;
  int bh = blockIdx.z;
  int b = bh >> 3, h = bh & 7;
  int r = t >> 3, c = (t & 7) * 4;
  const ushort* src = vbuf + ((size_t)b * SEQ + n0 + r) * 512 + h * 64 + d0 + c;
  union { uint2 v; ushort u[4]; } lv;
  lv.v = *(const uint2*)src;
#pragma unroll
  for (int j = 0; j < 4; j++) tile[r][c + j] = lv.u[j];
  __syncthreads();
  ushort* dst = vT + (((size_t)bh * 64) + d0 + r) * 2048 + n0 + c;
  union { uint2 v; ushort u[4]; } sv;
#pragma unroll
  for (int j = 0; j < 4; j++) sv.u[j] = tile[c + j][r];
  *(uint2*)dst = sv.v;
}

// ---------------------------------------------------------------------------
// GEMM, 128x128 tile, BK=64, 4 waves (2Mx2N), 32x32x16 MFMA, multi-tile:
// each block processes `ntile` row-tiles over the same column panel.
// Between tiles, the next tile's kt=0 staging is issued BEFORE the epilogue
// (buf0 WAR-safe: last read at kt=6, barrier since), so epilogue stores hide
// the next prologue's load latency; B (same col0) re-stages L2-hot.
// This amortizes the cold prologue 4x and removes the inter-round boundary
// (grid 256 = 1/CU, 1 round) without touching the verified sync structure.
// op 10: fused q/k/v/gates epilogue.  op 3: +bias+res -> f32 yout.
// ---------------------------------------------------------------------------
__global__ __launch_bounds__(256, 2) void gemm128_k(const ushort* __restrict__ A,
                                                    const ushort* __restrict__ Bt,
                                                    ushort* __restrict__ qb,
                                                    ushort* __restrict__ kb,
                                                    ushort* __restrict__ vbuf,
                                                    ushort* __restrict__ gsb,
                                                    float* __restrict__ yout,
                                                    const float* __restrict__ bias,
                                                    const float* __restrict__ res,
                                                    int op, int ntile) {
  __shared__ __align__(16) ushort As[2][128 * 64];
  __shared__ __align__(16) ushort Bs[2][128 * 64];
  int t = threadIdx.x;
  int nb = gridDim.x * gridDim.y;                 // %8 == 0
  int bid = blockIdx.y * gridDim.x + blockIdx.x;
  int swz = (bid & 7) * (nb >> 3) + (bid >> 3);   // XCD-contiguous panels
  int rowB = (swz / gridDim.x) * 128 * ntile;     // base row of this block
  int col0 = (swz % gridDim.x) * 128;

  int w = t >> 6, l = t & 63, l31 = l & 31, hi = l >> 5;
  int wm = w >> 1, wn = w & 1;                    // 2 x 2 wave grid, 64x64 each
  // staging: thread t covers rows srow + j*32 (j=0..3), 16B slot (t&7).
  int srow = t >> 3;                               // 0..31
  int ssl = (t & 7) ^ (srow & 7);                  // inverse-swizzled global slot
  const ushort* Bg = Bt + (size_t)(col0 + srow) * 512 + ssl * 8;
  // wave-uniform LDS base slot: lane l lands at slot wslot + l (+ j*256)
  int wslot = __builtin_amdgcn_readfirstlane((t >> 6) << 6);

#if GLOAD_DIRECT
#define STG(p, kt, Ag_)                                                         \
  do {                                                                          \
    gload16(Ag_ + (size_t)(kt) * 64 + 0 * 32 * 512, &As[p][(wslot +   0) * 8]); \
    gload16(Ag_ + (size_t)(kt) * 64 + 1 * 32 * 512, &As[p][(wslot + 256) * 8]); \
    gload16(Ag_ + (size_t)(kt) * 64 + 2 * 32 * 512, &As[p][(wslot + 512) * 8]); \
    gload16(Ag_ + (size_t)(kt) * 64 + 3 * 32 * 512, &As[p][(wslot + 768) * 8]); \
    gload16(Bg + (size_t)(kt) * 64 + 0 * 32 * 512,  &Bs[p][(wslot +   0) * 8]); \
    gload16(Bg + (size_t)(kt) * 64 + 1 * 32 * 512,  &Bs[p][(wslot + 256) * 8]); \
    gload16(Bg + (size_t)(kt) * 64 + 2 * 32 * 512,  &Bs[p][(wslot + 512) * 8]); \
    gload16(Bg + (size_t)(kt) * 64 + 3 * 32 * 512,  &Bs[p][(wslot + 768) * 8]); \
  } while (0)
#else
#define STG(p, kt, Ag_)                                                             \
  do {                                                                              \
    *(int4*)(&As[p][(t +   0) * 8]) = *(const int4*)(Ag_ + (size_t)(kt) * 64);      \
    *(int4*)(&As[p][(t + 256) * 8]) =                                               \
        *(const int4*)(Ag_ + (size_t)(kt) * 64 + 1 * 32 * 512);                     \
    *(int4*)(&As[p][(t + 512) * 8]) =                                               \
        *(const int4*)(Ag_ + (size_t)(kt) * 64 + 2 * 32 * 512);                     \
    *(int4*)(&As[p][(t + 768) * 8]) =                                               \
        *(const int4*)(Ag_ + (size_t)(kt) * 64 + 3 * 32 * 512);                     \
    *(int4*)(&Bs[p][(t +   0) * 8]) = *(const int4*)(Bg + (size_t)(kt) * 64);       \
    *(int4*)(&Bs[p][(t + 256) * 8]) =                                               \
        *(const int4*)(Bg + (size_t)(kt) * 64 + 1 * 32 * 512);                      \
    *(int4*)(&Bs[p][(t + 512) * 8]) =                                               \
        *(const int4*)(Bg + (size_t)(kt) * 64 + 2 * 32 * 512);                      \
    *(int4*)(&Bs[p][(t + 768) * 8]) =                                               \
        *(const int4*)(Bg + (size_t)(kt) * 64 + 3 * 32 * 512);                      \
  } while (0)
#endif

// swizzled fragment read: (row, 8-elem slot s) -> bf16x8
#define FRAG(p, M, r, s) \
  (*(const bf16x8*)(&M[p][((r) * 64) + ((((s) ^ ((r) & 7))) << 3)]))

  for (int tile = 0; tile < ntile; tile++) {
    int row0 = rowB + tile * 128;
    const ushort* Ag = A + (size_t)(row0 + srow) * 512 + ssl * 8;
    f32x16 acc[2][2] = {};

    if (tile == 0) {
      STG(0, 0, Ag);
      __syncthreads();
    }
    // tile > 0: buf0/kt=0 was prefetched before the previous epilogue and the
    // trailing __syncthreads established the staging invariant.

    for (int kt = 0; kt < 8; kt++) {
      int p = kt & 1;
      if (kt < 7) STG(p ^ 1, kt + 1, Ag);

      bf16x8 bfrag[2][4];
#pragma unroll
      for (int cb = 0; cb < 2; cb++)
#pragma unroll
        for (int kk = 0; kk < 4; kk++)
          bfrag[cb][kk] = FRAG(p, Bs, wn * 64 + cb * 32 + l31, kk * 2 + hi);

      __builtin_amdgcn_s_setprio(1);
#pragma unroll
      for (int rb = 0; rb < 2; rb++) {
        bf16x8 af[4];
#pragma unroll
        for (int kk = 0; kk < 4; kk++)
          af[kk] = FRAG(p, As, wm * 64 + rb * 32 + l31, kk * 2 + hi);
#pragma unroll
        for (int kk = 0; kk < 4; kk++) {
          acc[rb][0] = MFMA32(af[kk], bfrag[0][kk], acc[rb][0]);
          acc[rb][1] = MFMA32(af[kk], bfrag[1][kk], acc[rb][1]);
        }
      }
      __builtin_amdgcn_s_setprio(0);

      if (kt < 7) __syncthreads();
    }

    // prefetch next tile's kt=0 into buf0 BEFORE the epilogue: buf0 was last
    // read at kt=6 and a barrier separates us from that read (WAR safe). The
    // epilogue's stores then hide the prologue latency of tile+1.
    if (tile + 1 < ntile) {
      const ushort* Ag2 = Ag + (size_t)128 * 512;
      STG(0, 0, Ag2);
    }

    // epilogue: C/D 32x32 layout col=lane&31, row=(e&3)+8*(e>>2)+4*hi
#pragma unroll
    for (int rb = 0; rb < 2; rb++) {
#pragma unroll
      for (int cb = 0; cb < 2; cb++) {
#pragma unroll
        for (int e = 0; e < 16; e++) {
          int rr = (e & 3) + 8 * (e >> 2) + 4 * hi;
          int row = row0 + wm * 64 + rb * 32 + rr;
          int col = col0 + wn * 64 + cb * 32 + l31;
          float v = acc[rb][cb][e];
          if (op == 3) {
            v += bias[col] + res[(size_t)row * 512 + col];
            yout[(size_t)row * 512 + col] = v;
          } else {
            if (col0 < 512) {
              qb[(size_t)row * 512 + col] = f2bf(v * QSCALE);
            } else if (col0 < 1024) {
              kb[(size_t)row * 512 + (col - 512)] = f2bf(v);
            } else if (col0 < 1536) {
              vbuf[(size_t)row * 512 + (col - 1024)] = f2bf(v);
            } else {
              v += bias[col - 1536];
              v = 1.f / (1.f + __expf(-v));
              gsb[(size_t)row * 512 + (col - 1536)] = f2bf(v);
            }
          }
        }
      }
    }

    if (tile + 1 < ntile) __syncthreads();
  }
#undef STG
#undef FRAG
}

// ---------------------------------------------------------------------------
// Flash attention, 32x32 MFMA, swapped QK^T, exp2 softmax (no max-tracking).
// Double-buffered K/V LDS: one barrier per KV tile.
// Block: 256 q rows of one (b,h); 8 waves x 32 rows. KV tile = 64.
// lsum via MFMA ones-column (acco2) - same C/D row mapping as acco0.
// ---------------------------------------------------------------------------
__global__ __launch_bounds__(512) void attn_k(const ushort* __restrict__ q,
                                              const ushort* __restrict__ kbuf,
                                              const ushort* __restrict__ vT,
                                              const ushort* __restrict__ gs,
                                              ushort* __restrict__ gated) {
  __shared__ __align__(16) ushort Kl[2][64][72];
  __shared__ __align__(16) ushort Vl[2][64][72];   // [d][j]
  int t = threadIdx.x;
  int bid = blockIdx.x;
  int swz = (bid & 7) * 32 + (bid >> 3);        // XCD swizzle (256 % 8 == 0)
  int qt = swz & 7, bh = swz >> 3;              // 8 q-tiles x 32 bh
  int b = bh >> 3, h = bh & 7;
  int q0 = qt * 256;
  int w = t >> 6, l = t & 63;                    // w in 0..7
  int l31 = l & 31, hi = l >> 5;
  size_t base_n = (size_t)b * SEQ;

  const ushort* qp = q + (base_n + q0 + w * 32 + l31) * 512 + h * 64 + hi * 8;
  bf16x8 qf[4];
#pragma unroll
  for (int kd = 0; kd < 4; kd++)
    qf[kd] = *(const bf16x8*)(qp + kd * 16);

  bf16x8 vones;
#pragma unroll
  for (int j = 0; j < 8; j++) vones[j] = (short)0x3F80;  // bf16 1.0

  f32x16 acco0 = {}, acco1 = {}, acco2 = {};

  // staging: 512 threads, one K row + one V row each. srow 0..63.
  int srow = t >> 3, c8 = (t & 7) * 8;
  const ushort* kg = kbuf + (base_n + srow) * 512 + h * 64 + c8;
  const ushort* vg = vT + ((size_t)bh * 64 + srow) * 2048 + c8;

  // tile 0 -> LDS buf0
  int4 kA = *(const int4*)(kg);
  int4 vA = *(const int4*)(vg);
  *(int4*)((char*)Kl[0] + srow * 144 + c8 * 2) = kA;
  *(int4*)((char*)Vl[0] + srow * 144 + c8 * 2) = vA;
  // tile 1 -> regs
  kA = *(const int4*)(kg + (size_t)64 * 512);
  vA = *(const int4*)(vg + 64);
  __syncthreads();

  int p = 0;
  for (int jt = 0; jt < SEQ / 64; jt++) {
    // QK^T swapped: s[j][q], j-blocks of 32
    f32x16 s0 = {}, s1 = {};
    __builtin_amdgcn_s_setprio(1);
#pragma unroll
    for (int kd = 0; kd < 4; kd++) {
      bf16x8 k0 = *(const bf16x8*)((const char*)Kl[p] + l31 * 144 + kd * 32 + hi * 16);
      bf16x8 k1 = *(const bf16x8*)((const char*)Kl[p] + (32 + l31) * 144 + kd * 32 + hi * 16);
      s0 = MFMA32(k0, qf[kd], s0);
      s1 = MFMA32(k1, qf[kd], s1);
    }
    __builtin_amdgcn_s_setprio(0);

    // stage tile jt+1 regs -> LDS buf p^1 (overlaps softmax below)
    if (jt < SEQ / 64 - 1) {
      *(int4*)((char*)Kl[p ^ 1] + srow * 144 + c8 * 2) = kA;
      *(int4*)((char*)Vl[p ^ 1] + srow * 144 + c8 * 2) = vA;
    }

    // P = exp2(s); pack pairs to bf16 (sums come from the ones-MFMA below)
    uint32_t pk[16];
#pragma unroll
    for (int sg = 0; sg < 4; sg++) {
#pragma unroll
      for (int u = 0; u < 2; u++) {
        float a = __builtin_amdgcn_exp2f(s0[(sg << 2) | (u << 1)]);
        float c = __builtin_amdgcn_exp2f(s0[(sg << 2) | (u << 1) | 1]);
        pk[sg * 2 + u] = cvtpk(a, c);
      }
    }
#pragma unroll
    for (int sg = 0; sg < 4; sg++) {
#pragma unroll
      for (int u = 0; u < 2; u++) {
        float a = __builtin_amdgcn_exp2f(s1[(sg << 2) | (u << 1)]);
        float c = __builtin_amdgcn_exp2f(s1[(sg << 2) | (u << 1) | 1]);
        pk[8 + sg * 2 + u] = cvtpk(a, c);
      }
    }

    // PV: relayout P via permlane32_swap, MFMA with Vt (+ ones for lsum)
    __builtin_amdgcn_s_setprio(1);
#pragma unroll
    for (int jk = 0; jk < 4; jk++) {
      uint32_t x0 = pk[(2 * jk) * 2 + 0], y0 = pk[(2 * jk + 1) * 2 + 0];
      uint32_t x1 = pk[(2 * jk) * 2 + 1], y1 = pk[(2 * jk + 1) * 2 + 1];
      asm("v_permlane32_swap_b32 %0, %1" : "+v"(x0), "+v"(y0));
      asm("v_permlane32_swap_b32 %0, %1" : "+v"(x1), "+v"(y1));
      union { bf16x8 v; uint32_t u[4]; } pa;
      pa.u[0] = x0; pa.u[1] = x1; pa.u[2] = y0; pa.u[3] = y1;
      bf16x8 v0 = *(const bf16x8*)((const char*)Vl[p] + l31 * 144 + jk * 32 + hi * 16);
      bf16x8 v1 = *(const bf16x8*)((const char*)Vl[p] + (32 + l31) * 144 + jk * 32 + hi * 16);
      acco0 = MFMA32(pa.v, v0, acco0);
      acco1 = MFMA32(pa.v, v1, acco1);
      acco2 = MFMA32(pa.v, vones, acco2);
    }
    __builtin_amdgcn_s_setprio(0);

    if (jt < SEQ / 64 - 1) {
      __syncthreads();
      if (jt < SEQ / 64 - 2) {
        kA = *(const int4*)(kg + (size_t)(jt + 2) * 64 * 512);
        vA = *(const int4*)(vg + (jt + 2) * 64);
      }
      p ^= 1;
    }
  }

#pragma unroll
  for (int e = 0; e < 16; e++) {
    int qr = (e & 3) + 8 * (e >> 2) + 4 * hi;
    size_t row = base_n + q0 + w * 32 + qr;
    int col = h * 64 + l31;
    float rcp = 1.f / acco2[e];
    float v0 = acco0[e] * rcp * bf2f(gs[row * 512 + col]);
    float v1 = acco1[e] * rcp * bf2f(gs[row * 512 + col + 32]);
    gated[row * 512 + col] = f2bf(v0);
    gated[row * 512 + col + 32] = f2bf(v1);
  }
}

// ---------------------------------------------------------------------------
// LayerNorm over rows of 512, f32 in/out, wave per row.
// ---------------------------------------------------------------------------
__global__ __launch_bounds__(256) void ln_k(const float* __restrict__ y,
                                            const float* __restrict__ gamma,
                                            const float* __restrict__ beta,
                                            float* __restrict__ out) {
  int w = threadIdx.x >> 6, l = threadIdx.x & 63;
  size_t row = (size_t)blockIdx.x * 4 + w;
  const float4* yp = (const float4*)(y + row * 512);
  float4 a = yp[l * 2], b = yp[l * 2 + 1];
  float f[8] = {a.x, a.y, a.z, a.w, b.x, b.y, b.z, b.w};
  float sm = 0.f, sq = 0.f;
#pragma unroll
  for (int j = 0; j < 8; j++) { sm += f[j]; sq += f[j] * f[j]; }
#pragma unroll
  for (int off = 1; off < 64; off <<= 1) {
    sm += __shfl_xor(sm, off);
    sq += __shfl_xor(sq, off);
  }
  float mean = sm * (1.f / 512.f);
  float var = sq * (1.f / 512.f) - mean * mean;
  float rs = rsqrtf(var + 1e-5f);
  float4 g0 = ((const float4*)gamma)[l * 2], g1 = ((const float4*)gamma)[l * 2 + 1];
  float4 b0 = ((const float4*)beta)[l * 2],  b1 = ((const float4*)beta)[l * 2 + 1];
  float4 o0, o1;
  o0.x = (f[0] - mean) * rs * g0.x + b0.x;
  o0.y = (f[1] - mean) * rs * g0.y + b0.y;
  o0.z = (f[2] - mean) * rs * g0.z + b0.z;
  o0.w = (f[3] - mean) * rs * g0.w + b0.w;
  o1.x = (f[4] - mean) * rs * g1.x + b1.x;
  o1.y = (f[5] - mean) * rs * g1.y + b1.y;
  o1.z = (f[6] - mean) * rs * g1.z + b1.z;
  o1.w = (f[7] - mean) * rs * g1.w + b1.w;
  float4* op = (float4*)(out + row * 512);
  op[l * 2] = o0;
  op[l * 2 + 1] = o1;
}

// ---------------------------------------------------------------------------
extern "C" void kernel_launch(void* const* d_in, const int* in_sizes, int n_in,
                              void* d_out, int out_size, void* d_ws, size_t ws_size,
                              hipStream_t stream) {
  (void)in_sizes; (void)n_in; (void)out_size; (void)ws_size;
  const float* x     = (const float*)d_in[0];
  const float* Wq    = (const float*)d_in[1];
  const float* Wkv   = (const float*)d_in[2];
  const float* Wo    = (const float*)d_in[3];
  const float* bo    = (const float*)d_in[4];
  const float* Wg    = (const float*)d_in[5];
  const float* bg    = (const float*)d_in[6];
  const float* gamma = (const float*)d_in[7];
  const float* beta  = (const float*)d_in[8];

  char* ws = (char*)d_ws;
  ushort* xb    = (ushort*)(ws);                    //  8 MiB
  ushort* qbuf  = (ushort*)(ws + (8u  << 20));      //  8 MiB
  ushort* kbuf  = (ushort*)(ws + (16u << 20));      //  8 MiB
  ushort* vbuf  = (ushort*)(ws + (24u << 20));      //  8 MiB
  ushort* vT    = (ushort*)(ws + (32u << 20));      //  8 MiB
  ushort* gsb   = (ushort*)(ws + (40u << 20));      //  8 MiB
  ushort* gated = (ushort*)(ws + (48u << 20));      //  8 MiB
  float*  y     = (float*)(ws + (56u << 20));       // 16 MiB
  ushort* WT    = (ushort*)(ws + (72u << 20));      //  2 MiB  [2048][512]
  ushort* WoT   = (ushort*)(ws + (74u << 20));      // 0.5 MiB

  cvt_k<<<(NBATCH * SEQ * DMODEL / 8 + 255) / 256, 256, 0, stream>>>(
      x, xb, NBATCH * SEQ * DMODEL / 8);

  wtrans_k<<<dim3(80, 16), 256, 0, stream>>>(Wq, Wkv, Wg, Wo, WT, WoT);

  // fused q/k/v/gates projection: [8192,512] @ [2048,512]^T.
  // grid 256 = 1/CU, each block does 4 row-tiles (multi-tile, prologue-amortized)
  gemm128_k<<<dim3(16, 16), 256, 0, stream>>>(xb, WT, qbuf, kbuf, vbuf, gsb,
                                              nullptr, bg, nullptr, 10, 4);

  vtrans_k<<<dim3(64, 2, 32), 256, 0, stream>>>(vbuf, vT);

  attn_k<<<256, 512, 0, stream>>>(qbuf, kbuf, vT, gsb, gated);

  // out-projection: [8192,512] @ [512,512]^T, +bo+res -> f32 y
  gemm128_k<<<dim3(4, 64), 256, 0, stream>>>(gated, WoT, nullptr, nullptr,
                                             nullptr, nullptr, y, bo, x, 3, 1);

  ln_k<<<(NBATCH * SEQ) / 4, 256, 0, stream>>>(y, gamma, beta, (float*)d_out);
}

// Round 10
// 150.842 us; speedup vs baseline: 1.1807x; 1.1807x over previous
//
#include <hip/hip_runtime.h>
#include <hip/hip_bf16.h>
#include <stdint.h>
#include <stddef.h>

#define SEQ   2048
#define NBATCH 4
#define NHEAD  8
#define DMODEL 512

typedef __attribute__((ext_vector_type(8))) short bf16x8;
typedef __attribute__((ext_vector_type(4))) float f32x4;
typedef __attribute__((ext_vector_type(16))) float f32x16;

#define MFMA16(a, b, c) __builtin_amdgcn_mfma_f32_16x16x32_bf16(a, b, c, 0, 0, 0)
#define MFMA32(a, b, c) __builtin_amdgcn_mfma_f32_32x32x16_bf16(a, b, c, 0, 0, 0)

// 0.125 (softmax scale) * log2(e): QK^T lands in log2 domain -> P = exp2(s)
#define QSCALE 0.18033688011112042f

__device__ __forceinline__ float bf2f(ushort u) {
  union { uint32_t i; float f; } v; v.i = ((uint32_t)u) << 16; return v.f;
}
__device__ __forceinline__ ushort f2bf(float f) {
  union { float f; uint32_t i; } v; v.f = f;
  uint32_t u = v.i;
  return (ushort)((u + 0x7fffu + ((u >> 16) & 1u)) >> 16);
}
__device__ __forceinline__ uint32_t cvtpk(float lo, float hi) {
  uint32_t d;
  asm("v_cvt_pk_bf16_f32 %0, %1, %2" : "=v"(d) : "v"(lo), "v"(hi));
  return d;
}

#if __has_builtin(__builtin_amdgcn_global_load_lds)
__device__ __forceinline__ void gload16(const void* g, void* l) {
  __builtin_amdgcn_global_load_lds(
      (const __attribute__((address_space(1))) void*)g,
      (__attribute__((address_space(3))) void*)l, 16, 0, 0);
}
#define GLOAD_DIRECT 1
#else
#define GLOAD_DIRECT 0
#endif

// ---------------------------------------------------------------------------
// f32 -> bf16 elementwise convert. n8 = elements/8.
// ---------------------------------------------------------------------------
__global__ __launch_bounds__(256) void cvt_k(const float* __restrict__ in,
                                             ushort* __restrict__ out, int n8) {
  int i = blockIdx.x * 256 + threadIdx.x;
  if (i >= n8) return;
  const float4* p = (const float4*)(in + (size_t)i * 8);
  float4 a = p[0], b = p[1];
  union { int4 v; ushort u[8]; } o;
  o.u[0] = f2bf(a.x); o.u[1] = f2bf(a.y); o.u[2] = f2bf(a.z); o.u[3] = f2bf(a.w);
  o.u[4] = f2bf(b.x); o.u[5] = f2bf(b.y); o.u[6] = f2bf(b.z); o.u[7] = f2bf(b.w);
  *(int4*)(out + (size_t)i * 8) = o.v;
}

// ---------------------------------------------------------------------------
// All four weight transposes in one launch. W f32 [512,N] -> Wt bf16 [N,512].
// ---------------------------------------------------------------------------
__global__ __launch_bounds__(256) void wtrans_k(const float* __restrict__ Wq,
                                                const float* __restrict__ Wkv,
                                                const float* __restrict__ Wg,
                                                const float* __restrict__ Wo,
                                                ushort* __restrict__ WT,
                                                ushort* __restrict__ WoT) {
  __shared__ ushort tile[32][33];
  int bx = blockIdx.x;
  const float* W;
  ushort* dst;
  int N, nt;
  if (bx < 16)       { W = Wq;  dst = WT;              N = 512;  nt = bx; }
  else if (bx < 48)  { W = Wkv; dst = WT + 512 * 512;  N = 1024; nt = bx - 16; }
  else if (bx < 64)  { W = Wg;  dst = WT + 1536 * 512; N = 512;  nt = bx - 48; }
  else               { W = Wo;  dst = WoT;             N = 512;  nt = bx - 64; }
  int t = threadIdx.x;
  int n0 = nt * 32, k0 = blockIdx.y * 32;
  int r = t >> 3, c = (t & 7) * 4;
#pragma unroll
  for (int j = 0; j < 4; j++)
    tile[r][c + j] = f2bf(W[(size_t)(k0 + r) * N + n0 + c + j]);
  __syncthreads();
#pragma unroll
  for (int j = 0; j < 4; j++)
    dst[(size_t)(n0 + r) * 512 + k0 + c + j] = tile[c + j][r];
}

// ---------------------------------------------------------------------------
// bf16 transpose for V: vbuf [B*SEQ][512] head cols -> vT [bh][64][2048].
// 8B vectorized load/store (G13).
// ---------------------------------------------------------------------------
__global__ __launch_bounds__(256) void vtrans_k(const ushort* __restrict__ vbuf,
                                                ushort* __restrict__ vT) {
  __shared__ ushort tile[32][33];
  int t = threadIdx.x;
  int n0 = blockIdx.x * 32;
  int d0 = blockIdx.y * 32;
  int bh = blockIdx.z;
  int b = bh >> 3, h = bh & 7;
  int r = t >> 3, c = (t & 7) * 4;
  const ushort* src = vbuf + ((size_t)b * SEQ + n0 + r) * 512 + h * 64 + d0 + c;
  union { uint2 v; ushort u[4]; } lv;
  lv.v = *(const uint2*)src;
#pragma unroll
  for (int j = 0; j < 4; j++) tile[r][c + j] = lv.u[j];
  __syncthreads();
  ushort* dst = vT + (((size_t)bh * 64) + d0 + r) * 2048 + n0 + c;
  union { uint2 v; ushort u[4]; } sv;
#pragma unroll
  for (int j = 0; j < 4; j++) sv.u[j] = tile[c + j][r];
  *(uint2*)dst = sv.v;
}

// ---------------------------------------------------------------------------
// GEMM, 128x128 tile, BK=64, 4 waves (2Mx2N), 32x32x16 MFMA (round-8 exact:
// the verified best; grid 1024 -> 2 blocks/CU inter-block overlap).
// op 10: fused q/k/v/gates epilogue.  op 3: +bias+res -> f32 yout.
// ---------------------------------------------------------------------------
__global__ __launch_bounds__(256, 2) void gemm128_k(const ushort* __restrict__ A,
                                                    const ushort* __restrict__ Bt,
                                                    ushort* __restrict__ qb,
                                                    ushort* __restrict__ kb,
                                                    ushort* __restrict__ vbuf,
                                                    ushort* __restrict__ gsb,
                                                    float* __restrict__ yout,
                                                    const float* __restrict__ bias,
                                                    const float* __restrict__ res,
                                                    int op) {
  __shared__ __align__(16) ushort As[2][128 * 64];
  __shared__ __align__(16) ushort Bs[2][128 * 64];
  int t = threadIdx.x;
  int nb = gridDim.x * gridDim.y;                 // %8 == 0
  int bid = blockIdx.y * gridDim.x + blockIdx.x;
  int swz = (bid & 7) * (nb >> 3) + (bid >> 3);   // XCD-contiguous panels
  int row0 = (swz / gridDim.x) * 128, col0 = (swz % gridDim.x) * 128;

  int w = t >> 6, l = t & 63, l31 = l & 31, hi = l >> 5;
  int wm = w >> 1, wn = w & 1;                    // 2 x 2 wave grid, 64x64 each
  f32x16 acc[2][2] = {};

  // staging: thread t covers rows srow + j*32 (j=0..3), 16B slot (t&7).
  int srow = t >> 3;                               // 0..31
  int ssl = (t & 7) ^ (srow & 7);                  // inverse-swizzled global slot
  const ushort* Ag = A + (size_t)(row0 + srow) * 512 + ssl * 8;
  const ushort* Bg = Bt + (size_t)(col0 + srow) * 512 + ssl * 8;
  // wave-uniform LDS base slot: lane l lands at slot wslot + l (+ j*256)
  int wslot = __builtin_amdgcn_readfirstlane((t >> 6) << 6);

#if GLOAD_DIRECT
#define STG(p, kt)                                                             \
  do {                                                                         \
    gload16(Ag + (size_t)(kt) * 64 + 0 * 32 * 512, &As[p][(wslot +   0) * 8]); \
    gload16(Ag + (size_t)(kt) * 64 + 1 * 32 * 512, &As[p][(wslot + 256) * 8]); \
    gload16(Ag + (size_t)(kt) * 64 + 2 * 32 * 512, &As[p][(wslot + 512) * 8]); \
    gload16(Ag + (size_t)(kt) * 64 + 3 * 32 * 512, &As[p][(wslot + 768) * 8]); \
    gload16(Bg + (size_t)(kt) * 64 + 0 * 32 * 512, &Bs[p][(wslot +   0) * 8]); \
    gload16(Bg + (size_t)(kt) * 64 + 1 * 32 * 512, &Bs[p][(wslot + 256) * 8]); \
    gload16(Bg + (size_t)(kt) * 64 + 2 * 32 * 512, &Bs[p][(wslot + 512) * 8]); \
    gload16(Bg + (size_t)(kt) * 64 + 3 * 32 * 512, &Bs[p][(wslot + 768) * 8]); \
  } while (0)
#else
#define STG(p, kt)                                                                 \
  do {                                                                             \
    *(int4*)(&As[p][(t +   0) * 8]) = *(const int4*)(Ag + (size_t)(kt) * 64);      \
    *(int4*)(&As[p][(t + 256) * 8]) =                                              \
        *(const int4*)(Ag + (size_t)(kt) * 64 + 1 * 32 * 512);                     \
    *(int4*)(&As[p][(t + 512) * 8]) =                                              \
        *(const int4*)(Ag + (size_t)(kt) * 64 + 2 * 32 * 512);                     \
    *(int4*)(&As[p][(t + 768) * 8]) =                                              \
        *(const int4*)(Ag + (size_t)(kt) * 64 + 3 * 32 * 512);                     \
    *(int4*)(&Bs[p][(t +   0) * 8]) = *(const int4*)(Bg + (size_t)(kt) * 64);      \
    *(int4*)(&Bs[p][(t + 256) * 8]) =                                              \
        *(const int4*)(Bg + (size_t)(kt) * 64 + 1 * 32 * 512);                     \
    *(int4*)(&Bs[p][(t + 512) * 8]) =                                              \
        *(const int4*)(Bg + (size_t)(kt) * 64 + 2 * 32 * 512);                     \
    *(int4*)(&Bs[p][(t + 768) * 8]) =                                              \
        *(const int4*)(Bg + (size_t)(kt) * 64 + 3 * 32 * 512);                     \
  } while (0)
#endif

// swizzled fragment read: (row, 8-elem slot s) -> bf16x8
#define FRAG(p, M, r, s) \
  (*(const bf16x8*)(&M[p][((r) * 64) + ((((s) ^ ((r) & 7))) << 3)]))

  STG(0, 0);
  __syncthreads();

  for (int kt = 0; kt < 8; kt++) {
    int p = kt & 1;
    if (kt < 7) STG(p ^ 1, kt + 1);

    bf16x8 bfrag[2][4];
#pragma unroll
    for (int cb = 0; cb < 2; cb++)
#pragma unroll
      for (int kk = 0; kk < 4; kk++)
        bfrag[cb][kk] = FRAG(p, Bs, wn * 64 + cb * 32 + l31, kk * 2 + hi);

    __builtin_amdgcn_s_setprio(1);
#pragma unroll
    for (int rb = 0; rb < 2; rb++) {
      bf16x8 af[4];
#pragma unroll
      for (int kk = 0; kk < 4; kk++)
        af[kk] = FRAG(p, As, wm * 64 + rb * 32 + l31, kk * 2 + hi);
#pragma unroll
      for (int kk = 0; kk < 4; kk++) {
        acc[rb][0] = MFMA32(af[kk], bfrag[0][kk], acc[rb][0]);
        acc[rb][1] = MFMA32(af[kk], bfrag[1][kk], acc[rb][1]);
      }
    }
    __builtin_amdgcn_s_setprio(0);

    if (kt < 7) __syncthreads();
  }
#undef STG
#undef FRAG

  // epilogue: C/D 32x32 layout col=lane&31, row=(e&3)+8*(e>>2)+4*hi
#pragma unroll
  for (int rb = 0; rb < 2; rb++) {
#pragma unroll
    for (int cb = 0; cb < 2; cb++) {
#pragma unroll
      for (int e = 0; e < 16; e++) {
        int rr = (e & 3) + 8 * (e >> 2) + 4 * hi;
        int row = row0 + wm * 64 + rb * 32 + rr;
        int col = col0 + wn * 64 + cb * 32 + l31;
        float v = acc[rb][cb][e];
        if (op == 3) {
          v += bias[col] + res[(size_t)row * 512 + col];
          yout[(size_t)row * 512 + col] = v;
        } else {
          if (col0 < 512) {
            qb[(size_t)row * 512 + col] = f2bf(v * QSCALE);
          } else if (col0 < 1024) {
            kb[(size_t)row * 512 + (col - 512)] = f2bf(v);
          } else if (col0 < 1536) {
            vbuf[(size_t)row * 512 + (col - 1024)] = f2bf(v);
          } else {
            v += bias[col - 1536];
            v = 1.f / (1.f + __expf(-v));
            gsb[(size_t)row * 512 + (col - 1536)] = f2bf(v);
          }
        }
      }
    }
  }
}

// ---------------------------------------------------------------------------
// Flash attention, KV-SPLIT halves: block = (bh, qt, half), 16 KV tiles each.
// Grid 512 -> 2 blocks/CU -> 4 waves/SIMD: one block's softmax VALU overlaps
// the other's MFMA (the r2-counter signature MfmaUtil25+VALU52 = serial).
// No max-tracking => partials combine LINEARLY: numerator partial (bf16) to
// pb, row-sum partial (f32, from the ones-MFMA acco2) to lb. Gate/divide
// moved to combine_k. Per-wave math identical to the verified kernel.
// ---------------------------------------------------------------------------
__global__ __launch_bounds__(512) void attn_k(const ushort* __restrict__ q,
                                              const ushort* __restrict__ kbuf,
                                              const ushort* __restrict__ vT,
                                              ushort* __restrict__ pb,
                                              float* __restrict__ lb) {
  __shared__ __align__(16) ushort Kl[2][64][72];
  __shared__ __align__(16) ushort Vl[2][64][72];   // [d][j]
  int t = threadIdx.x;
  int bid = blockIdx.x;
  int swz = (bid & 7) * 64 + (bid >> 3);        // XCD swizzle (512 % 8 == 0)
  int half = swz & 1, qt = (swz >> 1) & 7, bh = swz >> 4;
  int b = bh >> 3, h = bh & 7;
  int q0 = qt * 256;
  int kv0 = half * 1024;                         // this block's KV range base
  int w = t >> 6, l = t & 63;                    // w in 0..7
  int l31 = l & 31, hi = l >> 5;
  size_t base_n = (size_t)b * SEQ;

  const ushort* qp = q + (base_n + q0 + w * 32 + l31) * 512 + h * 64 + hi * 8;
  bf16x8 qf[4];
#pragma unroll
  for (int kd = 0; kd < 4; kd++)
    qf[kd] = *(const bf16x8*)(qp + kd * 16);

  bf16x8 vones;
#pragma unroll
  for (int j = 0; j < 8; j++) vones[j] = (short)0x3F80;  // bf16 1.0

  f32x16 acco0 = {}, acco1 = {}, acco2 = {};

  // staging: 512 threads, one K row + one V row each. srow 0..63.
  int srow = t >> 3, c8 = (t & 7) * 8;
  const ushort* kg = kbuf + (base_n + kv0 + srow) * 512 + h * 64 + c8;
  const ushort* vg = vT + ((size_t)bh * 64 + srow) * 2048 + kv0 + c8;

  // tile 0 -> LDS buf0
  int4 kA = *(const int4*)(kg);
  int4 vA = *(const int4*)(vg);
  *(int4*)((char*)Kl[0] + srow * 144 + c8 * 2) = kA;
  *(int4*)((char*)Vl[0] + srow * 144 + c8 * 2) = vA;
  // tile 1 -> regs
  kA = *(const int4*)(kg + (size_t)64 * 512);
  vA = *(const int4*)(vg + 64);
  __syncthreads();

  int p = 0;
  const int NT = 1024 / 64;                      // 16 tiles per half
  for (int jt = 0; jt < NT; jt++) {
    // QK^T swapped: s[j][q], j-blocks of 32
    f32x16 s0 = {}, s1 = {};
    __builtin_amdgcn_s_setprio(1);
#pragma unroll
    for (int kd = 0; kd < 4; kd++) {
      bf16x8 k0 = *(const bf16x8*)((const char*)Kl[p] + l31 * 144 + kd * 32 + hi * 16);
      bf16x8 k1 = *(const bf16x8*)((const char*)Kl[p] + (32 + l31) * 144 + kd * 32 + hi * 16);
      s0 = MFMA32(k0, qf[kd], s0);
      s1 = MFMA32(k1, qf[kd], s1);
    }
    __builtin_amdgcn_s_setprio(0);

    // stage tile jt+1 regs -> LDS buf p^1 (overlaps softmax below)
    if (jt < NT - 1) {
      *(int4*)((char*)Kl[p ^ 1] + srow * 144 + c8 * 2) = kA;
      *(int4*)((char*)Vl[p ^ 1] + srow * 144 + c8 * 2) = vA;
    }

    // P = exp2(s); pack pairs to bf16 (sums come from the ones-MFMA below)
    uint32_t pk[16];
#pragma unroll
    for (int sg = 0; sg < 4; sg++) {
#pragma unroll
      for (int u = 0; u < 2; u++) {
        float a = __builtin_amdgcn_exp2f(s0[(sg << 2) | (u << 1)]);
        float c = __builtin_amdgcn_exp2f(s0[(sg << 2) | (u << 1) | 1]);
        pk[sg * 2 + u] = cvtpk(a, c);
      }
    }
#pragma unroll
    for (int sg = 0; sg < 4; sg++) {
#pragma unroll
      for (int u = 0; u < 2; u++) {
        float a = __builtin_amdgcn_exp2f(s1[(sg << 2) | (u << 1)]);
        float c = __builtin_amdgcn_exp2f(s1[(sg << 2) | (u << 1) | 1]);
        pk[8 + sg * 2 + u] = cvtpk(a, c);
      }
    }

    // PV: relayout P via permlane32_swap, MFMA with Vt (+ ones for lsum)
    __builtin_amdgcn_s_setprio(1);
#pragma unroll
    for (int jk = 0; jk < 4; jk++) {
      uint32_t x0 = pk[(2 * jk) * 2 + 0], y0 = pk[(2 * jk + 1) * 2 + 0];
      uint32_t x1 = pk[(2 * jk) * 2 + 1], y1 = pk[(2 * jk + 1) * 2 + 1];
      asm("v_permlane32_swap_b32 %0, %1" : "+v"(x0), "+v"(y0));
      asm("v_permlane32_swap_b32 %0, %1" : "+v"(x1), "+v"(y1));
      union { bf16x8 v; uint32_t u[4]; } pa;
      pa.u[0] = x0; pa.u[1] = x1; pa.u[2] = y0; pa.u[3] = y1;
      bf16x8 v0 = *(const bf16x8*)((const char*)Vl[p] + l31 * 144 + jk * 32 + hi * 16);
      bf16x8 v1 = *(const bf16x8*)((const char*)Vl[p] + (32 + l31) * 144 + jk * 32 + hi * 16);
      acco0 = MFMA32(pa.v, v0, acco0);
      acco1 = MFMA32(pa.v, v1, acco1);
      acco2 = MFMA32(pa.v, vones, acco2);
    }
    __builtin_amdgcn_s_setprio(0);

    if (jt < NT - 1) {
      __syncthreads();
      if (jt < NT - 2) {
        kA = *(const int4*)(kg + (size_t)(jt + 2) * 64 * 512);
        vA = *(const int4*)(vg + (jt + 2) * 64);
      }
      p ^= 1;
    }
  }

  // partial epilogue: numerator (bf16) to pb[half], row-sum (f32) to lb[half].
  ushort* pbh = pb + (size_t)half * 8192 * 512;
  float* lbh = lb + (size_t)half * 8192 * 8;
#pragma unroll
  for (int e = 0; e < 16; e++) {
    int qr = (e & 3) + 8 * (e >> 2) + 4 * hi;
    size_t row = base_n + q0 + w * 32 + qr;
    int col = h * 64 + l31;
    pbh[row * 512 + col] = f2bf(acco0[e]);
    pbh[row * 512 + col + 32] = f2bf(acco1[e]);
    if (l31 == 0) lbh[row * 8 + h] = acco2[e];   // acco2 duplicated over l31
  }
}

// ---------------------------------------------------------------------------
// Combine KV-split partials: gated = (p0+p1)/(l0+l1) * sigmoid-gate.
// One thread = 8 cols (one head-aligned bf16x8).
// ---------------------------------------------------------------------------
__global__ __launch_bounds__(256) void combine_k(const ushort* __restrict__ pb,
                                                 const float* __restrict__ lb,
                                                 const ushort* __restrict__ gs,
                                                 ushort* __restrict__ gated) {
  int idx = blockIdx.x * 256 + threadIdx.x;      // 8192*512/8 = 524288
  int row = idx >> 6;
  int c8 = (idx & 63) * 8;
  int h = c8 >> 6;
  const ushort* p0 = pb + (size_t)row * 512 + c8;
  const ushort* p1 = pb + (size_t)8192 * 512 + (size_t)row * 512 + c8;
  union { int4 v; ushort u[8]; } a, b, g, o;
  a.v = *(const int4*)p0;
  b.v = *(const int4*)p1;
  g.v = *(const int4*)(gs + (size_t)row * 512 + c8);
  float lsum = lb[(size_t)row * 8 + h] + lb[(size_t)8192 * 8 + (size_t)row * 8 + h];
  float rcp = 1.f / lsum;
#pragma unroll
  for (int j = 0; j < 8; j++)
    o.u[j] = f2bf((bf2f(a.u[j]) + bf2f(b.u[j])) * rcp * bf2f(g.u[j]));
  *(int4*)(gated + (size_t)row * 512 + c8) = o.v;
}

// ---------------------------------------------------------------------------
// LayerNorm over rows of 512, f32 in/out, wave per row.
// ---------------------------------------------------------------------------
__global__ __launch_bounds__(256) void ln_k(const float* __restrict__ y,
                                            const float* __restrict__ gamma,
                                            const float* __restrict__ beta,
                                            float* __restrict__ out) {
  int w = threadIdx.x >> 6, l = threadIdx.x & 63;
  size_t row = (size_t)blockIdx.x * 4 + w;
  const float4* yp = (const float4*)(y + row * 512);
  float4 a = yp[l * 2], b = yp[l * 2 + 1];
  float f[8] = {a.x, a.y, a.z, a.w, b.x, b.y, b.z, b.w};
  float sm = 0.f, sq = 0.f;
#pragma unroll
  for (int j = 0; j < 8; j++) { sm += f[j]; sq += f[j] * f[j]; }
#pragma unroll
  for (int off = 1; off < 64; off <<= 1) {
    sm += __shfl_xor(sm, off);
    sq += __shfl_xor(sq, off);
  }
  float mean = sm * (1.f / 512.f);
  float var = sq * (1.f / 512.f) - mean * mean;
  float rs = rsqrtf(var + 1e-5f);
  float4 g0 = ((const float4*)gamma)[l * 2], g1 = ((const float4*)gamma)[l * 2 + 1];
  float4 b0 = ((const float4*)beta)[l * 2],  b1 = ((const float4*)beta)[l * 2 + 1];
  float4 o0, o1;
  o0.x = (f[0] - mean) * rs * g0.x + b0.x;
  o0.y = (f[1] - mean) * rs * g0.y + b0.y;
  o0.z = (f[2] - mean) * rs * g0.z + b0.z;
  o0.w = (f[3] - mean) * rs * g0.w + b0.w;
  o1.x = (f[4] - mean) * rs * g1.x + b1.x;
  o1.y = (f[5] - mean) * rs * g1.y + b1.y;
  o1.z = (f[6] - mean) * rs * g1.z + b1.z;
  o1.w = (f[7] - mean) * rs * g1.w + b1.w;
  float4* op = (float4*)(out + row * 512);
  op[l * 2] = o0;
  op[l * 2 + 1] = o1;
}

// ---------------------------------------------------------------------------
extern "C" void kernel_launch(void* const* d_in, const int* in_sizes, int n_in,
                              void* d_out, int out_size, void* d_ws, size_t ws_size,
                              hipStream_t stream) {
  (void)in_sizes; (void)n_in; (void)out_size; (void)ws_size;
  const float* x     = (const float*)d_in[0];
  const float* Wq    = (const float*)d_in[1];
  const float* Wkv   = (const float*)d_in[2];
  const float* Wo    = (const float*)d_in[3];
  const float* bo    = (const float*)d_in[4];
  const float* Wg    = (const float*)d_in[5];
  const float* bg    = (const float*)d_in[6];
  const float* gamma = (const float*)d_in[7];
  const float* beta  = (const float*)d_in[8];

  char* ws = (char*)d_ws;
  ushort* xb    = (ushort*)(ws);                    //  8 MiB  (pb half0 after gemm)
  ushort* qbuf  = (ushort*)(ws + (8u  << 20));      //  8 MiB
  ushort* kbuf  = (ushort*)(ws + (16u << 20));      //  8 MiB
  ushort* vbuf  = (ushort*)(ws + (24u << 20));      //  8 MiB
  ushort* vT    = (ushort*)(ws + (32u << 20));      //  8 MiB
  ushort* gsb   = (ushort*)(ws + (40u << 20));      //  8 MiB
  ushort* gated = (ushort*)(ws + (48u << 20));      //  8 MiB
  float*  y     = (float*)(ws + (56u << 20));       // 16 MiB (pb half1 before outproj)
  ushort* WT    = (ushort*)(ws + (72u << 20));      //  2 MiB  [2048][512]
  ushort* WoT   = (ushort*)(ws + (74u << 20));      // 0.5 MiB
  float*  lb    = (float*)(ws + (75u << 20));       // 0.5 MiB lsum partials

  // pb: two 8 MiB halves, contiguous view starting at xb is NOT possible
  // (xb..qbuf adjacency would alias qbuf). Use xb for half0 via explicit
  // offset math in attn/combine: pb points at xb, half1 at y's region.
  // Simplest: pb = xb with half stride 8192*512; half1 must land in y.
  // xb + 8192*512 == ws + 8 MiB == qbuf (ALIAS!), so instead pass pb = xb
  // only if stride lands in free space. It does not; use y region for BOTH
  // halves: y spans 16 MiB = exactly 2 x 8 MiB bf16 partial buffers.
  ushort* pb = (ushort*)y;                          // halves at +0 / +8 MiB

  cvt_k<<<(NBATCH * SEQ * DMODEL / 8 + 255) / 256, 256, 0, stream>>>(
      x, xb, NBATCH * SEQ * DMODEL / 8);

  wtrans_k<<<dim3(80, 16), 256, 0, stream>>>(Wq, Wkv, Wg, Wo, WT, WoT);

  // fused q/k/v/gates projection: [8192,512] @ [2048,512]^T, 128^2 tiles
  gemm128_k<<<dim3(16, 64), 256, 0, stream>>>(xb, WT, qbuf, kbuf, vbuf, gsb,
                                              nullptr, bg, nullptr, 10);

  vtrans_k<<<dim3(64, 2, 32), 256, 0, stream>>>(vbuf, vT);

  // KV-split attention: 512 blocks = (bh, qt, half); partials to pb/lb
  attn_k<<<512, 512, 0, stream>>>(qbuf, kbuf, vT, pb, lb);

  combine_k<<<2048, 256, 0, stream>>>(pb, lb, gsb, gated);

  // out-projection: [8192,512] @ [512,512]^T, +bo+res -> f32 y
  // (y overlaps pb, but combine_k finished reading pb before this runs)
  gemm128_k<<<dim3(4, 64), 256, 0, stream>>>(gated, WoT, nullptr, nullptr,
                                             nullptr, nullptr, y, bo, x, 3);

  ln_k<<<(NBATCH * SEQ) / 4, 256, 0, stream>>>(y, gamma, beta, (float*)d_out);
}

// Round 11
// 132.167 us; speedup vs baseline: 1.3475x; 1.1413x over previous
//
#include <hip/hip_runtime.h>
#include <hip/hip_bf16.h>
#include <stdint.h>
#include <stddef.h>

#define SEQ   2048
#define NBATCH 4
#define NHEAD  8
#define DMODEL 512

typedef __attribute__((ext_vector_type(8))) short bf16x8;
typedef __attribute__((ext_vector_type(4))) float f32x4;
typedef __attribute__((ext_vector_type(16))) float f32x16;

#define MFMA16(a, b, c) __builtin_amdgcn_mfma_f32_16x16x32_bf16(a, b, c, 0, 0, 0)
#define MFMA32(a, b, c) __builtin_amdgcn_mfma_f32_32x32x16_bf16(a, b, c, 0, 0, 0)

// 0.125 (softmax scale) * log2(e): QK^T lands in log2 domain -> P = exp2(s)
#define QSCALE 0.18033688011112042f

__device__ __forceinline__ float bf2f(ushort u) {
  union { uint32_t i; float f; } v; v.i = ((uint32_t)u) << 16; return v.f;
}
__device__ __forceinline__ ushort f2bf(float f) {
  union { float f; uint32_t i; } v; v.f = f;
  uint32_t u = v.i;
  return (ushort)((u + 0x7fffu + ((u >> 16) & 1u)) >> 16);
}
__device__ __forceinline__ uint32_t cvtpk(float lo, float hi) {
  uint32_t d;
  asm("v_cvt_pk_bf16_f32 %0, %1, %2" : "=v"(d) : "v"(lo), "v"(hi));
  return d;
}

#if __has_builtin(__builtin_amdgcn_global_load_lds)
__device__ __forceinline__ void gload16(const void* g, void* l) {
  __builtin_amdgcn_global_load_lds(
      (const __attribute__((address_space(1))) void*)g,
      (__attribute__((address_space(3))) void*)l, 16, 0, 0);
}
#define GLOAD_DIRECT 1
#else
#define GLOAD_DIRECT 0
#endif

// ---------------------------------------------------------------------------
// f32 -> bf16 elementwise convert. n8 = elements/8.
// ---------------------------------------------------------------------------
__global__ __launch_bounds__(256) void cvt_k(const float* __restrict__ in,
                                             ushort* __restrict__ out, int n8) {
  int i = blockIdx.x * 256 + threadIdx.x;
  if (i >= n8) return;
  const float4* p = (const float4*)(in + (size_t)i * 8);
  float4 a = p[0], b = p[1];
  union { int4 v; ushort u[8]; } o;
  o.u[0] = f2bf(a.x); o.u[1] = f2bf(a.y); o.u[2] = f2bf(a.z); o.u[3] = f2bf(a.w);
  o.u[4] = f2bf(b.x); o.u[5] = f2bf(b.y); o.u[6] = f2bf(b.z); o.u[7] = f2bf(b.w);
  *(int4*)(out + (size_t)i * 8) = o.v;
}

// ---------------------------------------------------------------------------
// All four weight transposes in one launch. W f32 [512,N] -> Wt bf16 [N,512].
// ---------------------------------------------------------------------------
__global__ __launch_bounds__(256) void wtrans_k(const float* __restrict__ Wq,
                                                const float* __restrict__ Wkv,
                                                const float* __restrict__ Wg,
                                                const float* __restrict__ Wo,
                                                ushort* __restrict__ WT,
                                                ushort* __restrict__ WoT) {
  __shared__ ushort tile[32][33];
  int bx = blockIdx.x;
  const float* W;
  ushort* dst;
  int N, nt;
  if (bx < 16)       { W = Wq;  dst = WT;              N = 512;  nt = bx; }
  else if (bx < 48)  { W = Wkv; dst = WT + 512 * 512;  N = 1024; nt = bx - 16; }
  else if (bx < 64)  { W = Wg;  dst = WT + 1536 * 512; N = 512;  nt = bx - 48; }
  else               { W = Wo;  dst = WoT;             N = 512;  nt = bx - 64; }
  int t = threadIdx.x;
  int n0 = nt * 32, k0 = blockIdx.y * 32;
  int r = t >> 3, c = (t & 7) * 4;
#pragma unroll
  for (int j = 0; j < 4; j++)
    tile[r][c + j] = f2bf(W[(size_t)(k0 + r) * N + n0 + c + j]);
  __syncthreads();
#pragma unroll
  for (int j = 0; j < 4; j++)
    dst[(size_t)(n0 + r) * 512 + k0 + c + j] = tile[c + j][r];
}

// ---------------------------------------------------------------------------
// GEMM, 128x128 tile, BK=64, 4 waves (2Mx2N), 32x32x16 MFMA (round-8 exact
// structure; grid 1024 -> 2 blocks/CU inter-block overlap).
// op 10: fused q/k/v/gates epilogue. V-panel blocks (col0 in [1024,1536))
//        write V DIRECTLY TRANSPOSED to vT[bh][64][2048] via an in-LDS
//        transpose (reusing the staging LDS after a barrier) -> the
//        separate vtrans kernel (16 MiB traffic + launch) is deleted.
// op 3:  +bias+res -> f32 yout.
// ---------------------------------------------------------------------------
__global__ __launch_bounds__(256, 2) void gemm128_k(const ushort* __restrict__ A,
                                                    const ushort* __restrict__ Bt,
                                                    ushort* __restrict__ qb,
                                                    ushort* __restrict__ kb,
                                                    ushort* __restrict__ vT,
                                                    ushort* __restrict__ gsb,
                                                    float* __restrict__ yout,
                                                    const float* __restrict__ bias,
                                                    const float* __restrict__ res,
                                                    int op) {
  __shared__ __align__(16) ushort Sh[4 * 128 * 64];   // 64 KiB: As[2] | Bs[2]
#define ASB(p) (Sh + (p) * (128 * 64))
#define BSB(p) (Sh + 2 * (128 * 64) + (p) * (128 * 64))
  int t = threadIdx.x;
  int nb = gridDim.x * gridDim.y;                 // %8 == 0
  int bid = blockIdx.y * gridDim.x + blockIdx.x;
  int swz = (bid & 7) * (nb >> 3) + (bid >> 3);   // XCD-contiguous panels
  int row0 = (swz / gridDim.x) * 128, col0 = (swz % gridDim.x) * 128;

  int w = t >> 6, l = t & 63, l31 = l & 31, hi = l >> 5;
  int wm = w >> 1, wn = w & 1;                    // 2 x 2 wave grid, 64x64 each
  f32x16 acc[2][2] = {};

  // staging: thread t covers rows srow + j*32 (j=0..3), 16B slot (t&7).
  int srow = t >> 3;                               // 0..31
  int ssl = (t & 7) ^ (srow & 7);                  // inverse-swizzled global slot
  const ushort* Ag = A + (size_t)(row0 + srow) * 512 + ssl * 8;
  const ushort* Bg = Bt + (size_t)(col0 + srow) * 512 + ssl * 8;
  // wave-uniform LDS base slot: lane l lands at slot wslot + l (+ j*256)
  int wslot = __builtin_amdgcn_readfirstlane((t >> 6) << 6);

#if GLOAD_DIRECT
#define STG(p, kt)                                                              \
  do {                                                                          \
    gload16(Ag + (size_t)(kt) * 64 + 0 * 32 * 512, ASB(p) + (wslot +   0) * 8); \
    gload16(Ag + (size_t)(kt) * 64 + 1 * 32 * 512, ASB(p) + (wslot + 256) * 8); \
    gload16(Ag + (size_t)(kt) * 64 + 2 * 32 * 512, ASB(p) + (wslot + 512) * 8); \
    gload16(Ag + (size_t)(kt) * 64 + 3 * 32 * 512, ASB(p) + (wslot + 768) * 8); \
    gload16(Bg + (size_t)(kt) * 64 + 0 * 32 * 512, BSB(p) + (wslot +   0) * 8); \
    gload16(Bg + (size_t)(kt) * 64 + 1 * 32 * 512, BSB(p) + (wslot + 256) * 8); \
    gload16(Bg + (size_t)(kt) * 64 + 2 * 32 * 512, BSB(p) + (wslot + 512) * 8); \
    gload16(Bg + (size_t)(kt) * 64 + 3 * 32 * 512, BSB(p) + (wslot + 768) * 8); \
  } while (0)
#else
#define STG(p, kt)                                                                  \
  do {                                                                              \
    *(int4*)(ASB(p) + (t +   0) * 8) = *(const int4*)(Ag + (size_t)(kt) * 64);      \
    *(int4*)(ASB(p) + (t + 256) * 8) =                                              \
        *(const int4*)(Ag + (size_t)(kt) * 64 + 1 * 32 * 512);                      \
    *(int4*)(ASB(p) + (t + 512) * 8) =                                              \
        *(const int4*)(Ag + (size_t)(kt) * 64 + 2 * 32 * 512);                      \
    *(int4*)(ASB(p) + (t + 768) * 8) =                                              \
        *(const int4*)(Ag + (size_t)(kt) * 64 + 3 * 32 * 512);                      \
    *(int4*)(BSB(p) + (t +   0) * 8) = *(const int4*)(Bg + (size_t)(kt) * 64);      \
    *(int4*)(BSB(p) + (t + 256) * 8) =                                              \
        *(const int4*)(Bg + (size_t)(kt) * 64 + 1 * 32 * 512);                      \
    *(int4*)(BSB(p) + (t + 512) * 8) =                                              \
        *(const int4*)(Bg + (size_t)(kt) * 64 + 2 * 32 * 512);                      \
    *(int4*)(BSB(p) + (t + 768) * 8) =                                              \
        *(const int4*)(Bg + (size_t)(kt) * 64 + 3 * 32 * 512);                      \
  } while (0)
#endif

// swizzled fragment read: (base, row, 8-elem slot s) -> bf16x8
#define FRAG(Mb, r, s) \
  (*(const bf16x8*)(Mb + ((r) * 64) + ((((s) ^ ((r) & 7))) << 3)))

  STG(0, 0);
  __syncthreads();

  for (int kt = 0; kt < 8; kt++) {
    int p = kt & 1;
    if (kt < 7) STG(p ^ 1, kt + 1);

    bf16x8 bfrag[2][4];
#pragma unroll
    for (int cb = 0; cb < 2; cb++)
#pragma unroll
      for (int kk = 0; kk < 4; kk++)
        bfrag[cb][kk] = FRAG(BSB(p), wn * 64 + cb * 32 + l31, kk * 2 + hi);

    __builtin_amdgcn_s_setprio(1);
#pragma unroll
    for (int rb = 0; rb < 2; rb++) {
      bf16x8 af[4];
#pragma unroll
      for (int kk = 0; kk < 4; kk++)
        af[kk] = FRAG(ASB(p), wm * 64 + rb * 32 + l31, kk * 2 + hi);
#pragma unroll
      for (int kk = 0; kk < 4; kk++) {
        acc[rb][0] = MFMA32(af[kk], bfrag[0][kk], acc[rb][0]);
        acc[rb][1] = MFMA32(af[kk], bfrag[1][kk], acc[rb][1]);
      }
    }
    __builtin_amdgcn_s_setprio(0);

    if (kt < 7) __syncthreads();
  }
#undef STG
#undef FRAG

  // epilogue: C/D 32x32 layout col=lane&31, row=(e&3)+8*(e>>2)+4*hi
  if (op == 10 && col0 >= 1024 && col0 < 1536) {
    // V panel: bf16 transpose via LDS (stride 136 el = 272 B -> b128-aligned
    // reads), then coalesced 16B stores to vT[bh][64][2048].
    __syncthreads();                 // all waves done with staging LDS
    ushort* lt = Sh;                 // 128 x 136 = 34816 el <= 32768*... (64KiB ok)
#pragma unroll
    for (int rb = 0; rb < 2; rb++)
#pragma unroll
      for (int cb = 0; cb < 2; cb++)
#pragma unroll
        for (int e = 0; e < 16; e++) {
          int rr = (e & 3) + 8 * (e >> 2) + 4 * hi;
          int rowL = wm * 64 + rb * 32 + rr;
          int colL = wn * 64 + cb * 32 + l31;
          lt[colL * 136 + rowL] = f2bf(acc[rb][cb][e]);
        }
    __syncthreads();
    int b_ = row0 >> 11;             // batch
    int nb0 = row0 & 2047;           // n base within batch
#pragma unroll
    for (int r = 0; r < 8; r++) {
      int lin = r * 256 + t;         // 0..2047
      int dcol = lin >> 4, n8 = lin & 15;
      int vcol = (col0 - 1024) + dcol;
      int hh = vcol >> 6, dd = vcol & 63;
      bf16x8 v = *(const bf16x8*)(lt + dcol * 136 + n8 * 8);
      *(bf16x8*)(vT + (((size_t)(b_ * 8 + hh) * 64) + dd) * 2048 + nb0 + n8 * 8) = v;
    }
  } else {
#pragma unroll
    for (int rb = 0; rb < 2; rb++) {
#pragma unroll
      for (int cb = 0; cb < 2; cb++) {
#pragma unroll
        for (int e = 0; e < 16; e++) {
          int rr = (e & 3) + 8 * (e >> 2) + 4 * hi;
          int row = row0 + wm * 64 + rb * 32 + rr;
          int col = col0 + wn * 64 + cb * 32 + l31;
          float v = acc[rb][cb][e];
          if (op == 3) {
            v += bias[col] + res[(size_t)row * 512 + col];
            yout[(size_t)row * 512 + col] = v;
          } else {
            if (col0 < 512) {
              qb[(size_t)row * 512 + col] = f2bf(v * QSCALE);
            } else if (col0 < 1024) {
              kb[(size_t)row * 512 + (col - 512)] = f2bf(v);
            } else {
              v += bias[col - 1536];
              v = 1.f / (1.f + __expf(-v));
              gsb[(size_t)row * 512 + (col - 1536)] = f2bf(v);
            }
          }
        }
      }
    }
  }
#undef ASB
#undef BSB
}

// ---------------------------------------------------------------------------
// Flash attention, 32x32 MFMA, swapped QK^T, exp2 softmax (no max-tracking).
// Double-buffered K/V LDS: one barrier per KV tile.
// Block: 256 q rows of one (b,h); 8 waves x 32 rows. KV tile = 64.
// lsum via MFMA ones-column (acco2) - same C/D row mapping as acco0.
// ---------------------------------------------------------------------------
__global__ __launch_bounds__(512) void attn_k(const ushort* __restrict__ q,
                                              const ushort* __restrict__ kbuf,
                                              const ushort* __restrict__ vT,
                                              const ushort* __restrict__ gs,
                                              ushort* __restrict__ gated) {
  __shared__ __align__(16) ushort Kl[2][64][72];
  __shared__ __align__(16) ushort Vl[2][64][72];   // [d][j]
  int t = threadIdx.x;
  int bid = blockIdx.x;
  int swz = (bid & 7) * 32 + (bid >> 3);        // XCD swizzle (256 % 8 == 0)
  int qt = swz & 7, bh = swz >> 3;              // 8 q-tiles x 32 bh
  int b = bh >> 3, h = bh & 7;
  int q0 = qt * 256;
  int w = t >> 6, l = t & 63;                    // w in 0..7
  int l31 = l & 31, hi = l >> 5;
  size_t base_n = (size_t)b * SEQ;

  const ushort* qp = q + (base_n + q0 + w * 32 + l31) * 512 + h * 64 + hi * 8;
  bf16x8 qf[4];
#pragma unroll
  for (int kd = 0; kd < 4; kd++)
    qf[kd] = *(const bf16x8*)(qp + kd * 16);

  bf16x8 vones;
#pragma unroll
  for (int j = 0; j < 8; j++) vones[j] = (short)0x3F80;  // bf16 1.0

  f32x16 acco0 = {}, acco1 = {}, acco2 = {};

  // staging: 512 threads, one K row + one V row each. srow 0..63.
  int srow = t >> 3, c8 = (t & 7) * 8;
  const ushort* kg = kbuf + (base_n + srow) * 512 + h * 64 + c8;
  const ushort* vg = vT + ((size_t)bh * 64 + srow) * 2048 + c8;

  // tile 0 -> LDS buf0
  int4 kA = *(const int4*)(kg);
  int4 vA = *(const int4*)(vg);
  *(int4*)((char*)Kl[0] + srow * 144 + c8 * 2) = kA;
  *(int4*)((char*)Vl[0] + srow * 144 + c8 * 2) = vA;
  // tile 1 -> regs
  kA = *(const int4*)(kg + (size_t)64 * 512);
  vA = *(const int4*)(vg + 64);
  __syncthreads();

  int p = 0;
  for (int jt = 0; jt < SEQ / 64; jt++) {
    // QK^T swapped: s[j][q], j-blocks of 32
    f32x16 s0 = {}, s1 = {};
    __builtin_amdgcn_s_setprio(1);
#pragma unroll
    for (int kd = 0; kd < 4; kd++) {
      bf16x8 k0 = *(const bf16x8*)((const char*)Kl[p] + l31 * 144 + kd * 32 + hi * 16);
      bf16x8 k1 = *(const bf16x8*)((const char*)Kl[p] + (32 + l31) * 144 + kd * 32 + hi * 16);
      s0 = MFMA32(k0, qf[kd], s0);
      s1 = MFMA32(k1, qf[kd], s1);
    }
    __builtin_amdgcn_s_setprio(0);

    // stage tile jt+1 regs -> LDS buf p^1 (overlaps softmax below)
    if (jt < SEQ / 64 - 1) {
      *(int4*)((char*)Kl[p ^ 1] + srow * 144 + c8 * 2) = kA;
      *(int4*)((char*)Vl[p ^ 1] + srow * 144 + c8 * 2) = vA;
    }

    // P = exp2(s); pack pairs to bf16 (sums come from the ones-MFMA below)
    uint32_t pk[16];
#pragma unroll
    for (int sg = 0; sg < 4; sg++) {
#pragma unroll
      for (int u = 0; u < 2; u++) {
        float a = __builtin_amdgcn_exp2f(s0[(sg << 2) | (u << 1)]);
        float c = __builtin_amdgcn_exp2f(s0[(sg << 2) | (u << 1) | 1]);
        pk[sg * 2 + u] = cvtpk(a, c);
      }
    }
#pragma unroll
    for (int sg = 0; sg < 4; sg++) {
#pragma unroll
      for (int u = 0; u < 2; u++) {
        float a = __builtin_amdgcn_exp2f(s1[(sg << 2) | (u << 1)]);
        float c = __builtin_amdgcn_exp2f(s1[(sg << 2) | (u << 1) | 1]);
        pk[8 + sg * 2 + u] = cvtpk(a, c);
      }
    }

    // PV: relayout P via permlane32_swap, MFMA with Vt (+ ones for lsum)
    __builtin_amdgcn_s_setprio(1);
#pragma unroll
    for (int jk = 0; jk < 4; jk++) {
      uint32_t x0 = pk[(2 * jk) * 2 + 0], y0 = pk[(2 * jk + 1) * 2 + 0];
      uint32_t x1 = pk[(2 * jk) * 2 + 1], y1 = pk[(2 * jk + 1) * 2 + 1];
      asm("v_permlane32_swap_b32 %0, %1" : "+v"(x0), "+v"(y0));
      asm("v_permlane32_swap_b32 %0, %1" : "+v"(x1), "+v"(y1));
      union { bf16x8 v; uint32_t u[4]; } pa;
      pa.u[0] = x0; pa.u[1] = x1; pa.u[2] = y0; pa.u[3] = y1;
      bf16x8 v0 = *(const bf16x8*)((const char*)Vl[p] + l31 * 144 + jk * 32 + hi * 16);
      bf16x8 v1 = *(const bf16x8*)((const char*)Vl[p] + (32 + l31) * 144 + jk * 32 + hi * 16);
      acco0 = MFMA32(pa.v, v0, acco0);
      acco1 = MFMA32(pa.v, v1, acco1);
      acco2 = MFMA32(pa.v, vones, acco2);
    }
    __builtin_amdgcn_s_setprio(0);

    if (jt < SEQ / 64 - 1) {
      __syncthreads();
      if (jt < SEQ / 64 - 2) {
        kA = *(const int4*)(kg + (size_t)(jt + 2) * 64 * 512);
        vA = *(const int4*)(vg + (jt + 2) * 64);
      }
      p ^= 1;
    }
  }

#pragma unroll
  for (int e = 0; e < 16; e++) {
    int qr = (e & 3) + 8 * (e >> 2) + 4 * hi;
    size_t row = base_n + q0 + w * 32 + qr;
    int col = h * 64 + l31;
    float rcp = 1.f / acco2[e];
    float v0 = acco0[e] * rcp * bf2f(gs[row * 512 + col]);
    float v1 = acco1[e] * rcp * bf2f(gs[row * 512 + col + 32]);
    gated[row * 512 + col] = f2bf(v0);
    gated[row * 512 + col + 32] = f2bf(v1);
  }
}

// ---------------------------------------------------------------------------
// LayerNorm over rows of 512, f32 in/out, wave per row.
// ---------------------------------------------------------------------------
__global__ __launch_bounds__(256) void ln_k(const float* __restrict__ y,
                                            const float* __restrict__ gamma,
                                            const float* __restrict__ beta,
                                            float* __restrict__ out) {
  int w = threadIdx.x >> 6, l = threadIdx.x & 63;
  size_t row = (size_t)blockIdx.x * 4 + w;
  const float4* yp = (const float4*)(y + row * 512);
  float4 a = yp[l * 2], b = yp[l * 2 + 1];
  float f[8] = {a.x, a.y, a.z, a.w, b.x, b.y, b.z, b.w};
  float sm = 0.f, sq = 0.f;
#pragma unroll
  for (int j = 0; j < 8; j++) { sm += f[j]; sq += f[j] * f[j]; }
#pragma unroll
  for (int off = 1; off < 64; off <<= 1) {
    sm += __shfl_xor(sm, off);
    sq += __shfl_xor(sq, off);
  }
  float mean = sm * (1.f / 512.f);
  float var = sq * (1.f / 512.f) - mean * mean;
  float rs = rsqrtf(var + 1e-5f);
  float4 g0 = ((const float4*)gamma)[l * 2], g1 = ((const float4*)gamma)[l * 2 + 1];
  float4 b0 = ((const float4*)beta)[l * 2],  b1 = ((const float4*)beta)[l * 2 + 1];
  float4 o0, o1;
  o0.x = (f[0] - mean) * rs * g0.x + b0.x;
  o0.y = (f[1] - mean) * rs * g0.y + b0.y;
  o0.z = (f[2] - mean) * rs * g0.z + b0.z;
  o0.w = (f[3] - mean) * rs * g0.w + b0.w;
  o1.x = (f[4] - mean) * rs * g1.x + b1.x;
  o1.y = (f[5] - mean) * rs * g1.y + b1.y;
  o1.z = (f[6] - mean) * rs * g1.z + b1.z;
  o1.w = (f[7] - mean) * rs * g1.w + b1.w;
  float4* op = (float4*)(out + row * 512);
  op[l * 2] = o0;
  op[l * 2 + 1] = o1;
}

// ---------------------------------------------------------------------------
extern "C" void kernel_launch(void* const* d_in, const int* in_sizes, int n_in,
                              void* d_out, int out_size, void* d_ws, size_t ws_size,
                              hipStream_t stream) {
  (void)in_sizes; (void)n_in; (void)out_size; (void)ws_size;
  const float* x     = (const float*)d_in[0];
  const float* Wq    = (const float*)d_in[1];
  const float* Wkv   = (const float*)d_in[2];
  const float* Wo    = (const float*)d_in[3];
  const float* bo    = (const float*)d_in[4];
  const float* Wg    = (const float*)d_in[5];
  const float* bg    = (const float*)d_in[6];
  const float* gamma = (const float*)d_in[7];
  const float* beta  = (const float*)d_in[8];

  char* ws = (char*)d_ws;
  ushort* xb    = (ushort*)(ws);                    //  8 MiB
  ushort* qbuf  = (ushort*)(ws + (8u  << 20));      //  8 MiB
  ushort* kbuf  = (ushort*)(ws + (16u << 20));      //  8 MiB
  ushort* vT    = (ushort*)(ws + (32u << 20));      //  8 MiB [bh][64][2048]
  ushort* gsb   = (ushort*)(ws + (40u << 20));      //  8 MiB
  ushort* gated = (ushort*)(ws + (48u << 20));      //  8 MiB
  float*  y     = (float*)(ws + (56u << 20));       // 16 MiB
  ushort* WT    = (ushort*)(ws + (72u << 20));      //  2 MiB  [2048][512]
  ushort* WoT   = (ushort*)(ws + (74u << 20));      // 0.5 MiB

  cvt_k<<<(NBATCH * SEQ * DMODEL / 8 + 255) / 256, 256, 0, stream>>>(
      x, xb, NBATCH * SEQ * DMODEL / 8);

  wtrans_k<<<dim3(80, 16), 256, 0, stream>>>(Wq, Wkv, Wg, Wo, WT, WoT);

  // fused q/k/v/gates projection: [8192,512] @ [2048,512]^T, 128^2 tiles.
  // V panel lands directly transposed in vT (no vtrans kernel).
  gemm128_k<<<dim3(16, 64), 256, 0, stream>>>(xb, WT, qbuf, kbuf, vT, gsb,
                                              nullptr, bg, nullptr, 10);

  attn_k<<<256, 512, 0, stream>>>(qbuf, kbuf, vT, gsb, gated);

  // out-projection: [8192,512] @ [512,512]^T, +bo+res -> f32 y
  gemm128_k<<<dim3(4, 64), 256, 0, stream>>>(gated, WoT, nullptr, nullptr,
                                             nullptr, nullptr, y, bo, x, 3);

  ln_k<<<(NBATCH * SEQ) / 4, 256, 0, stream>>>(y, gamma, beta, (float*)d_out);
}